// Round 1
// baseline (6120.098 us; speedup 1.0000x reference)
//
#include <hip/hip_runtime.h>

#define MPTS 40960
#define NC 15
#define GX 1280
#define GY 948
#define HH 640
#define WW 474
#define CROPN 320
#define JW 6

// ---------- modified Bessel I0 (A&S 9.8.1 / 9.8.2), rel err < ~5e-7 ----------
__device__ __forceinline__ float i0f_dev(float x){
  if (x < 3.75f){
    float t = x*(1.0f/3.75f); t *= t;
    return 1.0f + t*(3.5156229f + t*(3.0899424f + t*(1.2067492f +
                 t*(0.2659732f + t*(0.0360768f + t*0.0045813f)))));
  } else {
    float t = 3.75f/x;
    float p = 0.39894228f + t*(0.01328592f + t*(0.00225319f + t*(-0.00157565f +
              t*(0.00916281f + t*(-0.02057706f + t*(0.02635537f +
              t*(-0.01647633f + t*0.00392377f)))))));
    return __expf(x)*rsqrtf(x)*p;
  }
}

// ---------- per-sample KB weights & flat grid indices ----------
__global__ void kb_weights(const float* __restrict__ ktraj,
                           float* __restrict__ w2, int* __restrict__ idx){
  int m = blockIdx.x*256 + threadIdx.x;
  if (m >= MPTS) return;
  const float PI2 = 6.28318530717958647692f;
  float tmx = ktraj[m]        * ((float)GX/PI2);
  float tmy = ktraj[MPTS + m] * ((float)GY/PI2);
  float wx[JW], wy[JW]; int ixv[JW], iyv[JW];
  float bx = floorf(tmx - 3.0f), by = floorf(tmy - 3.0f);
  #pragma unroll
  for (int j=0;j<JW;++j){
    float fx = bx + (float)(j+1);
    float u  = tmx - fx;
    float ax = 1.0f - u*u*(1.0f/9.0f);          // 1 - (2u/J)^2, J=6
    float w  = 0.0f;
    if (ax > 0.0f) w = i0f_dev(14.04f*sqrtf(fmaxf(ax,1e-12f)));
    wx[j] = w*(1.0f/6.0f);
    int ii = (int)fx; ii %= GX; if (ii<0) ii += GX; ixv[j] = ii;

    float fy = by + (float)(j+1);
    float v  = tmy - fy;
    float ay = 1.0f - v*v*(1.0f/9.0f);
    float wv = 0.0f;
    if (ay > 0.0f) wv = i0f_dev(14.04f*sqrtf(fmaxf(ay,1e-12f)));
    wy[j] = wv*(1.0f/6.0f);
    int jj = (int)fy; jj %= GY; if (jj<0) jj += GY; iyv[j] = jj;
  }
  float* wrow = w2  + (size_t)m*36;
  int*   irow = idx + (size_t)m*36;
  #pragma unroll
  for (int a=0;a<JW;++a)
    #pragma unroll
    for (int b=0;b<JW;++b){
      wrow[a*6+b] = wx[a]*wy[b];
      irow[a*6+b] = ixv[a]*GY + iyv[b];
    }
}

// ---------- gridding scatter: grid[c] += y[c,m] * w2[m,jj] at idx[m,jj] ----------
__global__ void kb_scatter(const float* __restrict__ kr, const float* __restrict__ ki,
                           const float* __restrict__ dc,
                           const float* __restrict__ w2, const int* __restrict__ idx,
                           float* __restrict__ grid, int c0){
  int m = blockIdx.x*256 + threadIdx.x;
  if (m >= MPTS) return;
  int cl = blockIdx.y;
  int c  = c0 + cl;
  float d  = dc[m];
  float yr = kr[(size_t)c*MPTS + m]*d;
  float yi = ki[(size_t)c*MPTS + m]*d;
  const float* w  = w2  + (size_t)m*36;
  const int*   id = idx + (size_t)m*36;
  float* g = grid + (size_t)cl*GX*GY*2;
  #pragma unroll
  for (int jj=0;jj<36;++jj){
    float wv = w[jj];
    int   p  = id[jj];
    atomicAdd(&g[2*p],   yr*wv);
    atomicAdd(&g[2*p+1], yi*wv);
  }
}

// ---------- partial inverse DFT along ky (948 -> 320 needed cols) ----------
// t[cl][q][kx] = sum_ky grid[cl][kx][ky] * exp(+2*pi*i*ky*ny(q)/948)
__global__ __launch_bounds__(320) void dft1(const float* __restrict__ grid,
                                            float* __restrict__ t){
  int kx = blockIdx.x;
  int cl = blockIdx.y;
  const float2* row = (const float2*)(grid + ((size_t)cl*GX + kx)*GY*2);
  __shared__ float2 lds[GY];
  for (int i=threadIdx.x; i<GY; i+=320) lds[i] = row[i];
  __syncthreads();
  int q  = threadIdx.x;
  int ny = (q < 160) ? (788 + q) : (q - 160);   // (col-160) mod 948 of output col
  const float STEP = 6.28318530717958647692f/(float)GY;
  float ar=0.f, ai=0.f; int rem=0;
  for (int ky=0; ky<GY; ++ky){
    float2 g = lds[ky];
    float ang = (float)rem * STEP;
    float s, c; __sincosf(ang, &s, &c);
    ar = fmaf(g.x, c, ar); ar = fmaf(-g.y, s, ar);
    ai = fmaf(g.x, s, ai); ai = fmaf( g.y, c, ai);
    rem += ny; if (rem >= GY) rem -= GY;
  }
  float2* tp = (float2*)t + ((size_t)cl*CROPN + q)*GX + kx;
  *tp = make_float2(ar, ai);
}

// ---------- partial inverse DFT along kx (1280 -> 320 rows) + coil combine ----------
__global__ __launch_bounds__(320) void dft2(const float* __restrict__ t,
                                            const float* __restrict__ smr,
                                            const float* __restrict__ smi,
                                            float* __restrict__ accum,
                                            int c0, int nb){
  int cc = blockIdx.x;      // output col
  int r  = threadIdx.x;     // output row
  int nx = (r < 160) ? (1120 + r) : (r - 160);  // (row-160) mod 1280
  const float STEP = 6.28318530717958647692f/(float)GX;
  __shared__ float2 lds[GX];
  float accr = 0.f, acci = 0.f;
  for (int cl=0; cl<nb; ++cl){
    const float2* row = (const float2*)t + ((size_t)cl*CROPN + cc)*GX;
    __syncthreads();
    for (int i=threadIdx.x; i<GX; i+=320) lds[i] = row[i];
    __syncthreads();
    float ar=0.f, ai=0.f; int rem=0;
    for (int kx=0; kx<GX; ++kx){
      float2 g = lds[kx];
      float ang = (float)rem * STEP;
      float s, c; __sincosf(ang, &s, &c);
      ar = fmaf(g.x, c, ar); ar = fmaf(-g.y, s, ar);
      ai = fmaf(g.x, s, ai); ai = fmaf( g.y, c, ai);
      rem += nx; if (rem >= GX) rem -= GX;
    }
    int c = c0 + cl;
    size_t sidx = ((size_t)c*HH + (160 + r))*WW + (77 + cc);
    float sr = smr[sidx], si = smi[sidx];
    // conj(smap) * img
    accr += sr*ar + si*ai;
    acci += sr*ai - si*ar;
  }
  size_t o = (size_t)r*CROPN + cc;
  accum[2*o]   += accr;   // single owner thread per (r,cc) -> no race
  accum[2*o+1] += acci;
}

// ---------- deapodization + magnitude ----------
__device__ __forceinline__ float deapod_f(float n, float G){
  float x = 3.14159265358979323846f * 6.0f * n / G;
  float z = 197.1216f - x*x;                    // BETA^2 = 14.04^2
  float sz = sqrtf(fabsf(z) + 1e-12f);
  float K;
  if (z > 0.0f){
    float e = __expf(sz);
    K = (e - 1.0f/e)*0.5f/sz;                   // sinh(sz)/sz
  } else {
    K = __sinf(sz)/sz;                          // sinc(sz/pi)
  }
  return 1.0f/K;
}

__global__ void final_mag(const float* __restrict__ accum, float* __restrict__ out){
  int i = blockIdx.x*256 + threadIdx.x;
  if (i >= CROPN*CROPN) return;
  int r  = i / CROPN;
  int cc = i - r*CROPN;
  float dx = deapod_f((float)(r  - 160), (float)GX);
  float dy = deapod_f((float)(cc - 160), (float)GY);
  float re = accum[2*i], im = accum[2*i+1];
  out[i] = sqrtf(re*re + im*im) * dx * dy;
}

extern "C" void kernel_launch(void* const* d_in, const int* in_sizes, int n_in,
                              void* d_out, int out_size, void* d_ws, size_t ws_size,
                              hipStream_t stream){
  const float* kr    = (const float*)d_in[0];
  const float* ki    = (const float*)d_in[1];
  const float* ktraj = (const float*)d_in[2];
  const float* dc    = (const float*)d_in[3];
  const float* smr   = (const float*)d_in[4];
  const float* smi   = (const float*)d_in[5];
  float* out = (float*)d_out;

  // workspace layout (floats)
  size_t w2_f    = (size_t)MPTS*36;
  size_t idx_f   = (size_t)MPTS*36;
  size_t acc_f   = (size_t)CROPN*CROPN*2;
  size_t base_f  = w2_f + idx_f + acc_f;
  size_t grid_pc = (size_t)GX*GY*2;         // per-coil grid floats
  size_t t_pc    = (size_t)CROPN*GX*2;      // per-coil t floats
  size_t percoil = grid_pc + t_pc;

  float* w2    = (float*)d_ws;
  int*   idx   = (int*)(w2 + w2_f);
  float* accum = (float*)(idx + idx_f);
  float* bbase = accum + acc_f;

  size_t avail = ws_size/4 > base_f ? ws_size/4 - base_f : 0;
  int nbmax = (int)(avail / percoil);
  if (nbmax < 1)  nbmax = 1;     // best effort
  if (nbmax > NC) nbmax = NC;

  float* gridp = bbase;
  float* tp    = bbase + (size_t)nbmax*grid_pc;

  hipMemsetAsync(accum, 0, acc_f*sizeof(float), stream);
  kb_weights<<<(MPTS+255)/256, 256, 0, stream>>>(ktraj, w2, idx);

  for (int c0 = 0; c0 < NC; c0 += nbmax){
    int nb = NC - c0; if (nb > nbmax) nb = nbmax;
    hipMemsetAsync(gridp, 0, (size_t)nb*grid_pc*sizeof(float), stream);
    kb_scatter<<<dim3((MPTS+255)/256, nb), 256, 0, stream>>>(kr, ki, dc, w2, idx, gridp, c0);
    dft1<<<dim3(GX, nb), 320, 0, stream>>>(gridp, tp);
    dft2<<<CROPN, 320, 0, stream>>>(tp, smr, smi, accum, c0, nb);
  }
  final_mag<<<(CROPN*CROPN+255)/256, 256, 0, stream>>>(accum, out);
}

// Round 2
// 2720.445 us; speedup vs baseline: 2.2497x; 2.2497x over previous
//
#include <hip/hip_runtime.h>

typedef __bf16 bf16;
typedef __attribute__((ext_vector_type(8))) __bf16 bf16x8;
typedef __attribute__((ext_vector_type(4))) float f32x4;

#define MPTS 40960
#define NC 15
#define GX 1280
#define GY 948
#define HH 640
#define WW 474
#define CROPN 320
#define JW 6

#define K1 1920   // [Gr(960 ky, padded) | Gi(960)]
#define N1 640    // 320 q x {re,im}
#define K2 2560   // [tr(1280 kx) | ti(1280)]
#define N2 384    // 320 r padded to 384

// ---------- modified Bessel I0 (A&S 9.8.1 / 9.8.2) ----------
__device__ __forceinline__ float i0f_dev(float x){
  if (x < 3.75f){
    float t = x*(1.0f/3.75f); t *= t;
    return 1.0f + t*(3.5156229f + t*(3.0899424f + t*(1.2067492f +
                 t*(0.2659732f + t*(0.0360768f + t*0.0045813f)))));
  } else {
    float t = 3.75f/x;
    float p = 0.39894228f + t*(0.01328592f + t*(0.00225319f + t*(-0.00157565f +
              t*(0.00916281f + t*(-0.02057706f + t*(0.02635537f +
              t*(-0.01647633f + t*0.00392377f)))))));
    return __expf(x)*rsqrtf(x)*p;
  }
}

// ---------- per-sample KB weights & flat grid indices ----------
__global__ void kb_weights(const float* __restrict__ ktraj,
                           float* __restrict__ w2, int* __restrict__ idx){
  int m = blockIdx.x*256 + threadIdx.x;
  if (m >= MPTS) return;
  const float PI2 = 6.28318530717958647692f;
  float tmx = ktraj[m]        * ((float)GX/PI2);
  float tmy = ktraj[MPTS + m] * ((float)GY/PI2);
  float wx[JW], wy[JW]; int ixv[JW], iyv[JW];
  float bx = floorf(tmx - 3.0f), by = floorf(tmy - 3.0f);
  #pragma unroll
  for (int j=0;j<JW;++j){
    float fx = bx + (float)(j+1);
    float u  = tmx - fx;
    float ax = 1.0f - u*u*(1.0f/9.0f);
    float w  = 0.0f;
    if (ax > 0.0f) w = i0f_dev(14.04f*sqrtf(fmaxf(ax,1e-12f)));
    wx[j] = w*(1.0f/6.0f);
    int ii = (int)fx; ii %= GX; if (ii<0) ii += GX; ixv[j] = ii;

    float fy = by + (float)(j+1);
    float v  = tmy - fy;
    float ay = 1.0f - v*v*(1.0f/9.0f);
    float wv = 0.0f;
    if (ay > 0.0f) wv = i0f_dev(14.04f*sqrtf(fmaxf(ay,1e-12f)));
    wy[j] = wv*(1.0f/6.0f);
    int jj = (int)fy; jj %= GY; if (jj<0) jj += GY; iyv[j] = jj;
  }
  float* wrow = w2  + (size_t)m*36;
  int*   irow = idx + (size_t)m*36;
  #pragma unroll
  for (int a=0;a<JW;++a)
    #pragma unroll
    for (int b=0;b<JW;++b){
      wrow[a*6+b] = wx[a]*wy[b];
      irow[a*6+b] = ixv[a]*GY + iyv[b];
    }
}

// ---------- gridding scatter ----------
__global__ void kb_scatter(const float* __restrict__ kr, const float* __restrict__ ki,
                           const float* __restrict__ dc,
                           const float* __restrict__ w2, const int* __restrict__ idx,
                           float* __restrict__ grid, int c0){
  int m = blockIdx.x*256 + threadIdx.x;
  if (m >= MPTS) return;
  int cl = blockIdx.y;
  int c  = c0 + cl;
  float d  = dc[m];
  float yr = kr[(size_t)c*MPTS + m]*d;
  float yi = ki[(size_t)c*MPTS + m]*d;
  const float* w  = w2  + (size_t)m*36;
  const int*   id = idx + (size_t)m*36;
  float* g = grid + (size_t)cl*GX*GY*2;
  #pragma unroll
  for (int jj=0;jj<36;++jj){
    float wv = w[jj];
    int   p  = id[jj];
    atomicAdd(&g[2*p],   yr*wv);
    atomicAdd(&g[2*p+1], yi*wv);
  }
}

// ---------- twiddle gen: B1t [N1][K1], B1t[2q+ri][half*960+ky] ----------
__global__ void gen_B1t(bf16* __restrict__ B1t){
  int i = blockIdx.x*256 + threadIdx.x;
  if (i >= N1*K1) return;
  int n = i / K1, k = i - n*K1;
  int q = n >> 1, ri = n & 1;
  int half = k / 960, ky = k - half*960;
  float v = 0.f;
  if (ky < GY){
    int ny = (q < 160) ? (788 + q) : (q - 160);
    int rem = (ky * ny) % GY;
    float ang = 6.28318530717958647692f * (float)rem / (float)GY;
    float s, c; sincosf(ang, &s, &c);
    // t_re needs [cos | -sin], t_im needs [sin | cos]
    v = ri ? (half ? c : s) : (half ? -s : c);
  }
  B1t[i] = (bf16)v;
}

// ---------- twiddle gen: W2t [N2][K2], W2t[r][part*1280+kx] ----------
__global__ void gen_W2t(bf16* __restrict__ W2t){
  int i = blockIdx.x*256 + threadIdx.x;
  if (i >= N2*K2) return;
  int n = i / K2, k = i - n*K2;
  float v = 0.f;
  if (n < CROPN){
    int part = k / 1280, kx = k - part*1280;
    int nx = (n < 160) ? (1120 + n) : (n - 160);
    int rem = (kx * nx) % GX;
    float ang = 6.28318530717958647692f * (float)rem / (float)GX;
    float s, c; sincosf(ang, &s, &c);
    v = part ? s : c;
  }
  W2t[i] = (bf16)v;
}

// ---------- pack grid(fp32 complex) -> A1 bf16 [bc*1280][K1] ----------
__global__ void pack_A1(const float* __restrict__ grid, bf16* __restrict__ A1, int total){
  int i = blockIdx.x*256 + threadIdx.x;     // (m, kgroup of 8)
  if (i >= total) return;
  int kg = i % (K1/8);
  int m  = i / (K1/8);                      // cl*1280 + kx
  int k0 = kg * 8;
  int half = k0 / 960;
  int ky0  = k0 - half*960;
  bf16x8 ov;
  #pragma unroll
  for (int j=0;j<8;++j){
    int ky = ky0 + j;
    float v = (ky < GY) ? grid[((size_t)m*GY + ky)*2 + half] : 0.f;
    ov[j] = (bf16)v;
  }
  *(bf16x8*)(A1 + (size_t)m*K1 + k0) = ov;
}

// ---------- pack C1(t, fp32) -> A2 bf16 [bc*640][K2] ----------
__global__ void pack_A2(const float* __restrict__ C1, bf16* __restrict__ A2, int total){
  int i = blockIdx.x*256 + threadIdx.x;     // (mr, kgroup of 8)
  if (i >= total) return;
  int kg = i % (K2/8);
  int mr = i / (K2/8);                      // cl*640 + 2q+ri
  int cl = mr / N1;
  int n  = mr - cl*N1;
  int q = n >> 1, ri = n & 1;
  int k0 = kg*8;
  int part = k0 / 1280, kx0 = k0 - part*1280;
  // ri0: [tr | -ti]  ri1: [ti | tr]
  int col = 2*q + (ri ^ part);
  float sign = (ri == 0 && part == 1) ? -1.f : 1.f;
  const float* base = C1 + ((size_t)cl*GX + kx0)*N1 + col;
  bf16x8 ov;
  #pragma unroll
  for (int j=0;j<8;++j) ov[j] = (bf16)(sign * base[(size_t)j*N1]);
  *(bf16x8*)(A2 + (size_t)mr*K2 + k0) = ov;
}

// ---------- bf16 GEMM: C[m][n] = sum_k A[m][k]*B[n][k]  (B stored transposed) ----------
#define BM 128
#define BN 128
#define BK 32
#define LDT 40   // padded LDS row stride in bf16

__global__ __launch_bounds__(256) void gemm_bt(const bf16* __restrict__ A,
                                               const bf16* __restrict__ B,
                                               float* __restrict__ C,
                                               int K, int ldc){
  __shared__ bf16 As[BM*LDT];
  __shared__ bf16 Bs[BM*LDT];
  int t = threadIdx.x;
  int lane = t & 63;
  int wave = t >> 6;
  int wm = wave >> 1, wn = wave & 1;
  size_t tileM = (size_t)blockIdx.x * BM;
  size_t tileN = (size_t)blockIdx.y * BN;

  const bf16* Ab = A + tileM * K;
  const bf16* Bb = B + tileN * K;

  f32x4 zero = {0.f, 0.f, 0.f, 0.f};
  f32x4 acc[4][4];
  #pragma unroll
  for (int m=0;m<4;++m)
    #pragma unroll
    for (int n=0;n<4;++n) acc[m][n] = zero;

  int r0 = t >> 2;              // 0..63
  int kc = (t & 3) * 8;         // 0,8,16,24
  size_t aoff = (size_t)r0 * K + kc;

  bf16x8 a0 = *(const bf16x8*)(Ab + aoff);
  bf16x8 a1 = *(const bf16x8*)(Ab + aoff + (size_t)64*K);
  bf16x8 b0 = *(const bf16x8*)(Bb + aoff);
  bf16x8 b1 = *(const bf16x8*)(Bb + aoff + (size_t)64*K);

  int lr = lane & 15, lk = (lane >> 4) * 8;

  for (int kt = 0; kt < K; kt += BK){
    __syncthreads();
    *(bf16x8*)(As + r0*LDT + kc)      = a0;
    *(bf16x8*)(As + (r0+64)*LDT + kc) = a1;
    *(bf16x8*)(Bs + r0*LDT + kc)      = b0;
    *(bf16x8*)(Bs + (r0+64)*LDT + kc) = b1;
    __syncthreads();

    bool more = (kt + BK) < K;
    if (more){
      size_t o = aoff + kt + BK;
      a0 = *(const bf16x8*)(Ab + o);
      a1 = *(const bf16x8*)(Ab + o + (size_t)64*K);
      b0 = *(const bf16x8*)(Bb + o);
      b1 = *(const bf16x8*)(Bb + o + (size_t)64*K);
    }

    bf16x8 af[4], bg[4];
    #pragma unroll
    for (int m=0;m<4;++m)
      af[m] = *(const bf16x8*)(As + (wm*64 + m*16 + lr)*LDT + lk);
    #pragma unroll
    for (int n=0;n<4;++n)
      bg[n] = *(const bf16x8*)(Bs + (wn*64 + n*16 + lr)*LDT + lk);
    #pragma unroll
    for (int m=0;m<4;++m)
      #pragma unroll
      for (int n=0;n<4;++n)
        acc[m][n] = __builtin_amdgcn_mfma_f32_16x16x32_bf16(af[m], bg[n], acc[m][n], 0, 0, 0);
  }

  int lrow = (lane >> 4) * 4;
  #pragma unroll
  for (int m=0;m<4;++m)
    #pragma unroll
    for (int n=0;n<4;++n){
      size_t row = tileM + wm*64 + m*16 + lrow;
      size_t col = tileN + wn*64 + n*16 + lr;
      #pragma unroll
      for (int r=0;r<4;++r)
        C[(row + r)*(size_t)ldc + col] = acc[m][n][r];
    }
}

// ---------- coil combine into accum ----------
__global__ void combine(const float* __restrict__ C2,
                        const float* __restrict__ smr, const float* __restrict__ smi,
                        float* __restrict__ accum, int c0, int bc){
  int i = blockIdx.x*256 + threadIdx.x;
  if (i >= CROPN*CROPN) return;
  int r = i / CROPN, q = i - r*CROPN;
  float ar = 0.f, ai = 0.f;
  for (int cl=0; cl<bc; ++cl){
    float re = C2[((size_t)cl*N1 + 2*q    )*N2 + r];
    float im = C2[((size_t)cl*N1 + 2*q + 1)*N2 + r];
    size_t sidx = ((size_t)(c0+cl)*HH + (160+r))*WW + (77+q);
    float sr = smr[sidx], si = smi[sidx];
    ar += sr*re + si*im;
    ai += sr*im - si*re;
  }
  accum[2*i] += ar; accum[2*i+1] += ai;
}

// ---------- deapodization + magnitude ----------
__device__ __forceinline__ float deapod_f(float n, float G){
  float x = 3.14159265358979323846f * 6.0f * n / G;
  float z = 197.1216f - x*x;
  float sz = sqrtf(fabsf(z) + 1e-12f);
  float K;
  if (z > 0.0f){
    float e = __expf(sz);
    K = (e - 1.0f/e)*0.5f/sz;
  } else {
    K = __sinf(sz)/sz;
  }
  return 1.0f/K;
}

__global__ void final_mag(const float* __restrict__ accum, float* __restrict__ out){
  int i = blockIdx.x*256 + threadIdx.x;
  if (i >= CROPN*CROPN) return;
  int r  = i / CROPN;
  int cc = i - r*CROPN;
  float dx = deapod_f((float)(r  - 160), (float)GX);
  float dy = deapod_f((float)(cc - 160), (float)GY);
  float re = accum[2*i], im = accum[2*i+1];
  out[i] = sqrtf(re*re + im*im) * dx * dy;
}

extern "C" void kernel_launch(void* const* d_in, const int* in_sizes, int n_in,
                              void* d_out, int out_size, void* d_ws, size_t ws_size,
                              hipStream_t stream){
  const float* kr    = (const float*)d_in[0];
  const float* ki    = (const float*)d_in[1];
  const float* ktraj = (const float*)d_in[2];
  const float* dc    = (const float*)d_in[3];
  const float* smr   = (const float*)d_in[4];
  const float* smi   = (const float*)d_in[5];
  float* out = (float*)d_out;

  // ---- workspace carve (bytes) ----
  const size_t w2_b    = (size_t)MPTS*36*4;          // 5,898,240
  const size_t idx_b   = (size_t)MPTS*36*4;
  const size_t acc_b   = (size_t)CROPN*CROPN*2*4;    // 819,200
  const size_t B1t_b   = (size_t)N1*K1*2;            // 2,457,600
  const size_t W2t_b   = (size_t)N2*K2*2;            // 1,966,080
  const size_t fixed_b = w2_b + idx_b + acc_b + B1t_b + W2t_b;

  const size_t grid_pc = (size_t)GX*GY*2*4;          // 9,707,520 (also hosts A2: 3,276,800)
  const size_t A1_pc   = (size_t)GX*K1*2;            // 4,915,200
  const size_t C1_pc   = (size_t)GX*N1*4;            // 3,276,800
  const size_t C2_pc   = (size_t)N1*N2*4;            //   983,040
  const size_t percoil = grid_pc + A1_pc + C1_pc + C2_pc;

  int bc = 1;
  if (ws_size > fixed_b + percoil){
    size_t b = (ws_size - fixed_b) / percoil;
    bc = (int)(b > NC ? NC : b);
    if (bc < 1) bc = 1;
  }

  char* p = (char*)d_ws;
  float* w2    = (float*)p; p += w2_b;
  int*   idx   = (int*)p;   p += idx_b;
  float* accum = (float*)p; p += acc_b;
  bf16*  B1t   = (bf16*)p;  p += B1t_b;
  bf16*  W2t   = (bf16*)p;  p += W2t_b;
  float* gridb = (float*)p;                 // aliased by A2 (grid dead by then)
  bf16*  A2    = (bf16*)p;  p += (size_t)bc*grid_pc;
  bf16*  A1    = (bf16*)p;  p += (size_t)bc*A1_pc;
  float* C1    = (float*)p; p += (size_t)bc*C1_pc;
  float* C2    = (float*)p; p += (size_t)bc*C2_pc;

  kb_weights<<<(MPTS+255)/256, 256, 0, stream>>>(ktraj, w2, idx);
  gen_B1t<<<(N1*K1+255)/256, 256, 0, stream>>>(B1t);
  gen_W2t<<<(N2*K2+255)/256, 256, 0, stream>>>(W2t);
  hipMemsetAsync(accum, 0, acc_b, stream);

  for (int c0 = 0; c0 < NC; c0 += bc){
    int nb = NC - c0; if (nb > bc) nb = bc;

    hipMemsetAsync(gridb, 0, (size_t)nb*grid_pc, stream);
    kb_scatter<<<dim3((MPTS+255)/256, nb), 256, 0, stream>>>(kr, ki, dc, w2, idx, gridb, c0);

    int tot1 = nb*GX*(K1/8);
    pack_A1<<<(tot1+255)/256, 256, 0, stream>>>(gridb, A1, tot1);
    gemm_bt<<<dim3(nb*(GX/BM), N1/BN), 256, 0, stream>>>(A1, B1t, C1, K1, N1);

    int tot2 = nb*N1*(K2/8);
    pack_A2<<<(tot2+255)/256, 256, 0, stream>>>(C1, A2, tot2);
    gemm_bt<<<dim3(nb*(N1/BM), N2/BN), 256, 0, stream>>>(A2, W2t, C2, K2, N2);

    combine<<<(CROPN*CROPN+255)/256, 256, 0, stream>>>(C2, smr, smi, accum, c0, nb);
  }
  final_mag<<<(CROPN*CROPN+255)/256, 256, 0, stream>>>(accum, out);
}

// Round 3
// 516.929 us; speedup vs baseline: 11.8393x; 5.2627x over previous
//
#include <hip/hip_runtime.h>

typedef __bf16 bf16;
typedef __attribute__((ext_vector_type(8))) __bf16 bf16x8;
typedef __attribute__((ext_vector_type(4))) float f32x4;

#define MPTS 40960
#define NC 15
#define GX 1280
#define GY 948
#define HH 640
#define WW 474
#define CROPN 320
#define JW 6
#define NCELL (GX*GY)          // 1,213,440

#define K1 1920   // [Gr(960 ky, padded) | Gi(960)]
#define N1 640    // 320 q x {re,im}
#define K2 2560   // [tr(1280 kx) | ti(1280)]
#define N2 384    // 320 r padded to 384

#define SCAN_TPB 256
#define SCAN_PER 16
#define SCAN_BLK (SCAN_TPB*SCAN_PER)                 // 4096
#define NSCAN ((NCELL + SCAN_BLK - 1)/SCAN_BLK)      // 297

// ---------- modified Bessel I0 (A&S 9.8.1 / 9.8.2) ----------
__device__ __forceinline__ float i0f_dev(float x){
  if (x < 3.75f){
    float t = x*(1.0f/3.75f); t *= t;
    return 1.0f + t*(3.5156229f + t*(3.0899424f + t*(1.2067492f +
                 t*(0.2659732f + t*(0.0360768f + t*0.0045813f)))));
  } else {
    float t = 3.75f/x;
    float p = 0.39894228f + t*(0.01328592f + t*(0.00225319f + t*(-0.00157565f +
              t*(0.00916281f + t*(-0.02057706f + t*(0.02635537f +
              t*(-0.01647633f + t*0.00392377f)))))));
    return __expf(x)*rsqrtf(x)*p;
  }
}

// ---------- recompute per-sample KB weights & 1D indices ----------
__device__ __forceinline__ void kb_compute(const float* __restrict__ ktraj, int m,
                                           float* wx, float* wy, int* ixv, int* iyv){
  const float PI2 = 6.28318530717958647692f;
  float tmx = ktraj[m]        * ((float)GX/PI2);
  float tmy = ktraj[MPTS + m] * ((float)GY/PI2);
  float bx = floorf(tmx - 3.0f), by = floorf(tmy - 3.0f);
  #pragma unroll
  for (int j=0;j<JW;++j){
    float fx = bx + (float)(j+1);
    float u  = tmx - fx;
    float ax = 1.0f - u*u*(1.0f/9.0f);
    float w  = 0.0f;
    if (ax > 0.0f) w = i0f_dev(14.04f*sqrtf(fmaxf(ax,1e-12f)));
    wx[j] = w*(1.0f/6.0f);
    int ii = (int)fx; ii %= GX; if (ii<0) ii += GX; ixv[j] = ii;

    float fy = by + (float)(j+1);
    float v  = tmy - fy;
    float ay = 1.0f - v*v*(1.0f/9.0f);
    float wv = 0.0f;
    if (ay > 0.0f) wv = i0f_dev(14.04f*sqrtf(fmaxf(ay,1e-12f)));
    wy[j] = wv*(1.0f/6.0f);
    int jj = (int)fy; jj %= GY; if (jj<0) jj += GY; iyv[j] = jj;
  }
}

// ---------- ydc[m][c][2] = kspace * dcomp ----------
__global__ void make_ydc(const float* __restrict__ kr, const float* __restrict__ ki,
                         const float* __restrict__ dc, float* __restrict__ ydc){
  int m = blockIdx.x*256 + threadIdx.x;
  if (m >= MPTS) return;
  float d = dc[m];
  #pragma unroll
  for (int c=0;c<NC;++c){
    ydc[((size_t)m*NC + c)*2    ] = kr[(size_t)c*MPTS + m]*d;
    ydc[((size_t)m*NC + c)*2 + 1] = ki[(size_t)c*MPTS + m]*d;
  }
}

// ---------- CSR build: histogram ----------
__global__ void hist_build(const float* __restrict__ ktraj, int* __restrict__ hist){
  int m = blockIdx.x*256 + threadIdx.x;
  if (m >= MPTS) return;
  float wx[JW], wy[JW]; int ixv[JW], iyv[JW];
  kb_compute(ktraj, m, wx, wy, ixv, iyv);
  #pragma unroll
  for (int a=0;a<JW;++a)
    #pragma unroll
    for (int b=0;b<JW;++b)
      atomicAdd(&hist[ixv[a]*GY + iyv[b]], 1);
}

// ---------- scan stage 1: per-block sums ----------
__global__ __launch_bounds__(SCAN_TPB) void scan_part(const int* __restrict__ hist,
                                                      int* __restrict__ bsum){
  int b = blockIdx.x, t = threadIdx.x;
  int base = b*SCAN_BLK + t*SCAN_PER;
  int s = 0;
  #pragma unroll
  for (int j=0;j<SCAN_PER;++j){
    int i = base + j;
    if (i < NCELL) s += hist[i];
  }
  __shared__ int red[SCAN_TPB];
  red[t] = s; __syncthreads();
  for (int off=SCAN_TPB/2; off>0; off>>=1){
    if (t < off) red[t] += red[t+off];
    __syncthreads();
  }
  if (t == 0) bsum[b] = red[0];
}

// ---------- scan stage 2: exclusive scan of block sums (single block) ----------
__global__ __launch_bounds__(512) void scan_bsum(int* __restrict__ bsum){
  __shared__ int s[512];
  int t = threadIdx.x;
  s[t] = (t < NSCAN) ? bsum[t] : 0;
  __syncthreads();
  for (int off=1; off<512; off<<=1){
    int v = (t >= off) ? s[t-off] : 0;
    __syncthreads();
    s[t] += v;
    __syncthreads();
  }
  if (t < NSCAN) bsum[t] = (t == 0) ? 0 : s[t-1];
}

// ---------- scan stage 3: write starts into cursor ----------
__global__ __launch_bounds__(SCAN_TPB) void scan_final(const int* __restrict__ hist,
                                                       const int* __restrict__ bsum,
                                                       int* __restrict__ cursor){
  int b = blockIdx.x, t = threadIdx.x;
  int base = b*SCAN_BLK + t*SCAN_PER;
  int v[SCAN_PER]; int s = 0;
  #pragma unroll
  for (int j=0;j<SCAN_PER;++j){
    int i = base + j;
    v[j] = (i < NCELL) ? hist[i] : 0;
    s += v[j];
  }
  __shared__ int sc[SCAN_TPB];
  sc[t] = s; __syncthreads();
  for (int off=1; off<SCAN_TPB; off<<=1){
    int x = (t >= off) ? sc[t-off] : 0;
    __syncthreads();
    sc[t] += x;
    __syncthreads();
  }
  int run = bsum[b] + ((t == 0) ? 0 : sc[t-1]);
  #pragma unroll
  for (int j=0;j<SCAN_PER;++j){
    int i = base + j;
    if (i < NCELL) cursor[i] = run;
    run += v[j];
  }
}

// ---------- CSR build: fill entries (mutates cursor start -> start+count) ----------
__global__ void fill_build(const float* __restrict__ ktraj, int* __restrict__ cursor,
                           int2* __restrict__ entries){
  int m = blockIdx.x*256 + threadIdx.x;
  if (m >= MPTS) return;
  float wx[JW], wy[JW]; int ixv[JW], iyv[JW];
  kb_compute(ktraj, m, wx, wy, ixv, iyv);
  #pragma unroll
  for (int a=0;a<JW;++a)
    #pragma unroll
    for (int b=0;b<JW;++b){
      int cell = ixv[a]*GY + iyv[b];
      int pos = atomicAdd(&cursor[cell], 1);
      entries[pos] = make_int2(m, __float_as_int(wx[a]*wy[b]));
    }
}

// ---------- gather: grid cell accumulates its contributions, writes bf16 A1 ----------
template<int BC>
__global__ __launch_bounds__(256) void gather_A1(const int* __restrict__ cursor,
                                                 const int* __restrict__ hist,
                                                 const int2* __restrict__ entries,
                                                 const float* __restrict__ ydc,
                                                 bf16* __restrict__ A1, int c0){
  int i = blockIdx.x*256 + threadIdx.x;      // kx*960 + kp
  if (i >= GX*960) return;
  int kx = i/960, kp = i - kx*960;
  float ar[BC], ai[BC];
  #pragma unroll
  for (int c=0;c<BC;++c){ ar[c]=0.f; ai[c]=0.f; }
  if (kp < GY){
    int cell = kx*GY + kp;
    int end = cursor[cell];
    int beg = end - hist[cell];
    for (int e=beg; e<end; ++e){
      int2 en = entries[e];
      float w = __int_as_float(en.y);
      const float* yp = ydc + ((size_t)en.x*NC + c0)*2;
      #pragma unroll
      for (int c=0;c<BC;++c){
        ar[c] = fmaf(w, yp[2*c],   ar[c]);
        ai[c] = fmaf(w, yp[2*c+1], ai[c]);
      }
    }
  }
  #pragma unroll
  for (int c=0;c<BC;++c){
    bf16* row = A1 + ((size_t)c*GX + kx)*K1;
    row[kp]       = (bf16)ar[c];
    row[960 + kp] = (bf16)ai[c];
  }
}

// ---------- twiddle gen: B1t [N1][K1] ----------
__global__ void gen_B1t(bf16* __restrict__ B1t){
  int i = blockIdx.x*256 + threadIdx.x;
  if (i >= N1*K1) return;
  int n = i / K1, k = i - n*K1;
  int q = n >> 1, ri = n & 1;
  int half = k / 960, ky = k - half*960;
  float v = 0.f;
  if (ky < GY){
    int ny = (q < 160) ? (788 + q) : (q - 160);
    int rem = (ky * ny) % GY;
    float ang = 6.28318530717958647692f * (float)rem / (float)GY;
    float s, c; sincosf(ang, &s, &c);
    v = ri ? (half ? c : s) : (half ? -s : c);
  }
  B1t[i] = (bf16)v;
}

// ---------- twiddle gen: W2t [N2][K2] ----------
__global__ void gen_W2t(bf16* __restrict__ W2t){
  int i = blockIdx.x*256 + threadIdx.x;
  if (i >= N2*K2) return;
  int n = i / K2, k = i - n*K2;
  float v = 0.f;
  if (n < CROPN){
    int part = k / 1280, kx = k - part*1280;
    int nx = (n < 160) ? (1120 + n) : (n - 160);
    int rem = (kx * nx) % GX;
    float ang = 6.28318530717958647692f * (float)rem / (float)GX;
    float s, c; sincosf(ang, &s, &c);
    v = part ? s : c;
  }
  W2t[i] = (bf16)v;
}

// ---------- pack C1(t, fp32) -> A2 bf16 [bc*640][K2] ----------
__global__ void pack_A2(const float* __restrict__ C1, bf16* __restrict__ A2, int total){
  int i = blockIdx.x*256 + threadIdx.x;
  if (i >= total) return;
  int kg = i % (K2/8);
  int mr = i / (K2/8);
  int cl = mr / N1;
  int n  = mr - cl*N1;
  int q = n >> 1, ri = n & 1;
  int k0 = kg*8;
  int part = k0 / 1280, kx0 = k0 - part*1280;
  int col = 2*q + (ri ^ part);
  float sign = (ri == 0 && part == 1) ? -1.f : 1.f;
  const float* base = C1 + ((size_t)cl*GX + kx0)*N1 + col;
  bf16x8 ov;
  #pragma unroll
  for (int j=0;j<8;++j) ov[j] = (bf16)(sign * base[(size_t)j*N1]);
  *(bf16x8*)(A2 + (size_t)mr*K2 + k0) = ov;
}

// ---------- bf16 GEMM: C[m][n] = sum_k A[m][k]*B[n][k] ----------
#define BM 128
#define BN 128
#define BK 32
#define LDT 40

__global__ __launch_bounds__(256) void gemm_bt(const bf16* __restrict__ A,
                                               const bf16* __restrict__ B,
                                               float* __restrict__ C,
                                               int K, int ldc){
  __shared__ bf16 As[BM*LDT];
  __shared__ bf16 Bs[BM*LDT];
  int t = threadIdx.x;
  int lane = t & 63;
  int wave = t >> 6;
  int wm = wave >> 1, wn = wave & 1;
  size_t tileM = (size_t)blockIdx.x * BM;
  size_t tileN = (size_t)blockIdx.y * BN;

  const bf16* Ab = A + tileM * K;
  const bf16* Bb = B + tileN * K;

  f32x4 zero = {0.f, 0.f, 0.f, 0.f};
  f32x4 acc[4][4];
  #pragma unroll
  for (int m=0;m<4;++m)
    #pragma unroll
    for (int n=0;n<4;++n) acc[m][n] = zero;

  int r0 = t >> 2;
  int kc = (t & 3) * 8;
  size_t aoff = (size_t)r0 * K + kc;

  bf16x8 a0 = *(const bf16x8*)(Ab + aoff);
  bf16x8 a1 = *(const bf16x8*)(Ab + aoff + (size_t)64*K);
  bf16x8 b0 = *(const bf16x8*)(Bb + aoff);
  bf16x8 b1 = *(const bf16x8*)(Bb + aoff + (size_t)64*K);

  int lr = lane & 15, lk = (lane >> 4) * 8;

  for (int kt = 0; kt < K; kt += BK){
    __syncthreads();
    *(bf16x8*)(As + r0*LDT + kc)      = a0;
    *(bf16x8*)(As + (r0+64)*LDT + kc) = a1;
    *(bf16x8*)(Bs + r0*LDT + kc)      = b0;
    *(bf16x8*)(Bs + (r0+64)*LDT + kc) = b1;
    __syncthreads();

    bool more = (kt + BK) < K;
    if (more){
      size_t o = aoff + kt + BK;
      a0 = *(const bf16x8*)(Ab + o);
      a1 = *(const bf16x8*)(Ab + o + (size_t)64*K);
      b0 = *(const bf16x8*)(Bb + o);
      b1 = *(const bf16x8*)(Bb + o + (size_t)64*K);
    }

    bf16x8 af[4], bg[4];
    #pragma unroll
    for (int m=0;m<4;++m)
      af[m] = *(const bf16x8*)(As + (wm*64 + m*16 + lr)*LDT + lk);
    #pragma unroll
    for (int n=0;n<4;++n)
      bg[n] = *(const bf16x8*)(Bs + (wn*64 + n*16 + lr)*LDT + lk);
    #pragma unroll
    for (int m=0;m<4;++m)
      #pragma unroll
      for (int n=0;n<4;++n)
        acc[m][n] = __builtin_amdgcn_mfma_f32_16x16x32_bf16(af[m], bg[n], acc[m][n], 0, 0, 0);
  }

  int lrow = (lane >> 4) * 4;
  #pragma unroll
  for (int m=0;m<4;++m)
    #pragma unroll
    for (int n=0;n<4;++n){
      size_t row = tileM + wm*64 + m*16 + lrow;
      size_t col = tileN + wn*64 + n*16 + lr;
      #pragma unroll
      for (int r=0;r<4;++r)
        C[(row + r)*(size_t)ldc + col] = acc[m][n][r];
    }
}

// ---------- coil combine into accum ----------
__global__ void combine(const float* __restrict__ C2,
                        const float* __restrict__ smr, const float* __restrict__ smi,
                        float* __restrict__ accum, int c0, int bc){
  int i = blockIdx.x*256 + threadIdx.x;
  if (i >= CROPN*CROPN) return;
  int r = i / CROPN, q = i - r*CROPN;
  float ar = 0.f, ai = 0.f;
  for (int cl=0; cl<bc; ++cl){
    float re = C2[((size_t)cl*N1 + 2*q    )*N2 + r];
    float im = C2[((size_t)cl*N1 + 2*q + 1)*N2 + r];
    size_t sidx = ((size_t)(c0+cl)*HH + (160+r))*WW + (77+q);
    float sr = smr[sidx], si = smi[sidx];
    ar += sr*re + si*im;
    ai += sr*im - si*re;
  }
  accum[2*i] += ar; accum[2*i+1] += ai;
}

// ---------- deapodization + magnitude ----------
__device__ __forceinline__ float deapod_f(float n, float G){
  float x = 3.14159265358979323846f * 6.0f * n / G;
  float z = 197.1216f - x*x;
  float sz = sqrtf(fabsf(z) + 1e-12f);
  float K;
  if (z > 0.0f){
    float e = __expf(sz);
    K = (e - 1.0f/e)*0.5f/sz;
  } else {
    K = __sinf(sz)/sz;
  }
  return 1.0f/K;
}

__global__ void final_mag(const float* __restrict__ accum, float* __restrict__ out){
  int i = blockIdx.x*256 + threadIdx.x;
  if (i >= CROPN*CROPN) return;
  int r  = i / CROPN;
  int cc = i - r*CROPN;
  float dx = deapod_f((float)(r  - 160), (float)GX);
  float dy = deapod_f((float)(cc - 160), (float)GY);
  float re = accum[2*i], im = accum[2*i+1];
  out[i] = sqrtf(re*re + im*im) * dx * dy;
}

extern "C" void kernel_launch(void* const* d_in, const int* in_sizes, int n_in,
                              void* d_out, int out_size, void* d_ws, size_t ws_size,
                              hipStream_t stream){
  const float* kr    = (const float*)d_in[0];
  const float* ki    = (const float*)d_in[1];
  const float* ktraj = (const float*)d_in[2];
  const float* dc    = (const float*)d_in[3];
  const float* smr   = (const float*)d_in[4];
  const float* smi   = (const float*)d_in[5];
  float* out = (float*)d_out;

  // ---- workspace carve (bytes) ----
  const size_t acc_b   = (size_t)CROPN*CROPN*2*4;    //   819,200
  const size_t B1t_b   = (size_t)N1*K1*2;            // 2,457,600
  const size_t W2t_b   = (size_t)N2*K2*2;            // 1,966,080
  const size_t ydc_b   = (size_t)MPTS*NC*2*4;        // 4,915,200
  const size_t hist_b  = (size_t)NCELL*4;            // 4,853,760
  const size_t curs_b  = (size_t)NCELL*4;
  const size_t bsum_b  = 2048*4;
  const size_t ent_b   = (size_t)MPTS*36*8;          // 11,796,480
  const size_t fixed_b = acc_b+B1t_b+W2t_b+ydc_b+hist_b+curs_b+bsum_b+ent_b;  // ~31.7 MB

  const size_t A1_pc   = (size_t)GX*K1*2;            // 4,915,200 (A2 aliases A1)
  const size_t C1_pc   = (size_t)GX*N1*4;            // 3,276,800
  const size_t C2_pc   = (size_t)N1*N2*4;            //   983,040
  const size_t percoil = A1_pc + C1_pc + C2_pc;      // 9,175,040

  int bc = 1;
  if (ws_size > fixed_b + percoil){
    size_t b = (ws_size - fixed_b) / percoil;
    bc = (int)(b > 8 ? 8 : b);
    if (bc < 1) bc = 1;
  }

  char* p = (char*)d_ws;
  float* accum  = (float*)p; p += acc_b;
  bf16*  B1t    = (bf16*)p;  p += B1t_b;
  bf16*  W2t    = (bf16*)p;  p += W2t_b;
  float* ydc    = (float*)p; p += ydc_b;
  int*   hist   = (int*)p;   p += hist_b;
  int*   cursor = (int*)p;   p += curs_b;
  int*   bsum   = (int*)p;   p += bsum_b;
  int2*  entries= (int2*)p;  p += ent_b;
  bf16*  A1     = (bf16*)p;
  bf16*  A2     = (bf16*)p;  p += (size_t)bc*A1_pc;   // A2 aliases A1 (A1 dead after GEMM1)
  float* C1     = (float*)p; p += (size_t)bc*C1_pc;
  float* C2     = (float*)p; p += (size_t)bc*C2_pc;

  // ---- one-time builds ----
  make_ydc<<<(MPTS+255)/256, 256, 0, stream>>>(kr, ki, dc, ydc);
  hipMemsetAsync(hist, 0, hist_b, stream);
  hist_build<<<(MPTS+255)/256, 256, 0, stream>>>(ktraj, hist);
  scan_part<<<NSCAN, SCAN_TPB, 0, stream>>>(hist, bsum);
  scan_bsum<<<1, 512, 0, stream>>>(bsum);
  scan_final<<<NSCAN, SCAN_TPB, 0, stream>>>(hist, bsum, cursor);
  fill_build<<<(MPTS+255)/256, 256, 0, stream>>>(ktraj, cursor, entries);
  gen_B1t<<<(N1*K1+255)/256, 256, 0, stream>>>(B1t);
  gen_W2t<<<(N2*K2+255)/256, 256, 0, stream>>>(W2t);
  hipMemsetAsync(accum, 0, acc_b, stream);

  // ---- per coil-batch pipeline ----
  for (int c0 = 0; c0 < NC; c0 += bc){
    int nb = NC - c0; if (nb > bc) nb = bc;

    int gblocks = (GX*960 + 255)/256;
    switch (nb){
      case 1: gather_A1<1><<<gblocks,256,0,stream>>>(cursor,hist,entries,ydc,A1,c0); break;
      case 2: gather_A1<2><<<gblocks,256,0,stream>>>(cursor,hist,entries,ydc,A1,c0); break;
      case 3: gather_A1<3><<<gblocks,256,0,stream>>>(cursor,hist,entries,ydc,A1,c0); break;
      case 4: gather_A1<4><<<gblocks,256,0,stream>>>(cursor,hist,entries,ydc,A1,c0); break;
      case 5: gather_A1<5><<<gblocks,256,0,stream>>>(cursor,hist,entries,ydc,A1,c0); break;
      case 6: gather_A1<6><<<gblocks,256,0,stream>>>(cursor,hist,entries,ydc,A1,c0); break;
      case 7: gather_A1<7><<<gblocks,256,0,stream>>>(cursor,hist,entries,ydc,A1,c0); break;
      default: gather_A1<8><<<gblocks,256,0,stream>>>(cursor,hist,entries,ydc,A1,c0); break;
    }

    gemm_bt<<<dim3(nb*(GX/BM), N1/BN), 256, 0, stream>>>(A1, B1t, C1, K1, N1);

    int tot2 = nb*N1*(K2/8);
    pack_A2<<<(tot2+255)/256, 256, 0, stream>>>(C1, A2, tot2);
    gemm_bt<<<dim3(nb*(N1/BM), N2/BN), 256, 0, stream>>>(A2, W2t, C2, K2, N2);

    combine<<<(CROPN*CROPN+255)/256, 256, 0, stream>>>(C2, smr, smi, accum, c0, nb);
  }
  final_mag<<<(CROPN*CROPN+255)/256, 256, 0, stream>>>(accum, out);
}